// Round 1
// baseline (1300.853 us; speedup 1.0000x reference)
//
#include <hip/hip_runtime.h>
#include <math.h>

#define NH 16
#define HD 64

__device__ __forceinline__ void fma4(float4& c, float a, const float4& b) {
    c.x += a * b.x; c.y += a * b.y; c.z += a * b.z; c.w += a * b.w;
}

// C = A[M,K] @ B[K,N], 128x128 tile, BK=16, 256 threads, 8x8 per thread
// MODE 0: plain row-major write to C0 (ldc = N)
// MODE 1: qkv scatter into head layout [b,h,n,d]; Q (cols 0..1023) scaled by 0.125
template<int MODE>
__global__ __launch_bounds__(256, 2)
void gemm_tile(const float* __restrict__ A, const float* __restrict__ B,
               float* __restrict__ C0, float* __restrict__ C1, float* __restrict__ C2,
               int M, int K, int N)
{
    __shared__ float As[16][128];   // transposed: As[k][m]
    __shared__ float Bs[16][132];   // padded

    const int t  = threadIdx.x;
    const int tx = t & 15, ty = t >> 4;
    const int m0 = blockIdx.y * 128, n0 = blockIdx.x * 128;

    // staging indices
    const int ar = t >> 1;            // A tile row 0..127
    const int ak = (t & 1) << 3;      // A k offset 0 or 8
    const int bk = t >> 4;            // B tile k row 0..15
    const int bc = (t & 15) << 3;     // B tile col (8 floats per thread)

    const float* Ap = A + (size_t)(m0 + ar) * K + ak;
    const float* Bp = B + (size_t)bk * N + n0 + bc;

    float4 acc[2][4][2];
    #pragma unroll
    for (int ih = 0; ih < 2; ih++)
        #pragma unroll
        for (int ii = 0; ii < 4; ii++)
            #pragma unroll
            for (int jh = 0; jh < 2; jh++)
                acc[ih][ii][jh] = make_float4(0.f, 0.f, 0.f, 0.f);

    // prefetch first tile into regs
    float4 a0 = *(const float4*)(Ap);
    float4 a1 = *(const float4*)(Ap + 4);
    float4 b0 = *(const float4*)(Bp);
    float4 b1 = *(const float4*)(Bp + 4);

    for (int k0 = 0; k0 < K; k0 += 16) {
        __syncthreads();   // previous iteration's LDS reads done
        As[ak+0][ar] = a0.x; As[ak+1][ar] = a0.y; As[ak+2][ar] = a0.z; As[ak+3][ar] = a0.w;
        As[ak+4][ar] = a1.x; As[ak+5][ar] = a1.y; As[ak+6][ar] = a1.z; As[ak+7][ar] = a1.w;
        *(float4*)&Bs[bk][bc]     = b0;
        *(float4*)&Bs[bk][bc + 4] = b1;
        __syncthreads();
        if (k0 + 16 < K) {   // prefetch next tile; latency hides under compute below
            a0 = *(const float4*)(Ap + k0 + 16);
            a1 = *(const float4*)(Ap + k0 + 20);
            b0 = *(const float4*)(Bp + (size_t)(k0 + 16) * N);
            b1 = *(const float4*)(Bp + (size_t)(k0 + 16) * N + 4);
        }
        #pragma unroll
        for (int kk = 0; kk < 16; kk++) {
            float4 av0 = *(const float4*)&As[kk][ty * 4];
            float4 av1 = *(const float4*)&As[kk][ty * 4 + 64];
            float4 bv0 = *(const float4*)&Bs[kk][tx * 4];
            float4 bv1 = *(const float4*)&Bs[kk][tx * 4 + 64];
            float  ra[2][4] = {{av0.x, av0.y, av0.z, av0.w}, {av1.x, av1.y, av1.z, av1.w}};
            float4 rb[2]    = {bv0, bv1};
            #pragma unroll
            for (int ih = 0; ih < 2; ih++)
                #pragma unroll
                for (int ii = 0; ii < 4; ii++)
                    #pragma unroll
                    for (int jh = 0; jh < 2; jh++)
                        fma4(acc[ih][ii][jh], ra[ih][ii], rb[jh]);
        }
    }

    if (MODE == 0) {
        #pragma unroll
        for (int ih = 0; ih < 2; ih++)
            #pragma unroll
            for (int ii = 0; ii < 4; ii++) {
                int row = m0 + ih * 64 + ty * 4 + ii;
                #pragma unroll
                for (int jh = 0; jh < 2; jh++)
                    *(float4*)&C0[(size_t)row * N + n0 + jh * 64 + tx * 4] = acc[ih][ii][jh];
            }
    } else {
        #pragma unroll
        for (int jh = 0; jh < 2; jh++) {
            int j      = n0 + jh * 64 + tx * 4;
            int sel    = j >> 10;
            int within = j & 1023;
            int h      = within >> 6;
            int d      = within & 63;
            float* dst = (sel == 0) ? C0 : (sel == 1) ? C1 : C2;
            float  sc  = (sel == 0) ? 0.125f : 1.0f;   // bake 1/sqrt(64) into Q (exact)
            #pragma unroll
            for (int ih = 0; ih < 2; ih++)
                #pragma unroll
                for (int ii = 0; ii < 4; ii++) {
                    int row = m0 + ih * 64 + ty * 4 + ii;   // = b*1024 + n
                    int bb = row >> 10, n = row & 1023;
                    float4 v = acc[ih][ii][jh];
                    v.x *= sc; v.y *= sc; v.z *= sc; v.w *= sc;
                    *(float4*)&dst[((size_t)((bb * NH + h) * 1024 + n)) * HD + d] = v;
                }
        }
    }
}

// Flash-style attention, fp32. Block = 256 threads handles one (b, h, 64-row q-tile).
// Q is pre-scaled by 1/8. K/V tiles (64x64) time-share one LDS buffer.
__global__ __launch_bounds__(256, 2)
void attn_kernel(const float* __restrict__ Q, const float* __restrict__ K,
                 const float* __restrict__ V, float* __restrict__ O)
{
    __shared__ float Qs[64][68];
    __shared__ float KVs[64][68];
    __shared__ float Ps[64][68];

    const int t  = threadIdx.x;
    const int tx = t & 15, ty = t >> 4;
    const int qt = blockIdx.x, h = blockIdx.y, b = blockIdx.z;

    const size_t headoff = (size_t)(b * NH + h) * 1024 * HD;
    const float* Qp = Q + headoff + (size_t)qt * 64 * HD;
    const float* Kp = K + headoff;
    const float* Vp = V + headoff;

    const int sr = t >> 2, sc = (t & 3) * 16;   // staging: row, col-base (4 float4s)

    // stage Q tile (made visible by the first __syncthreads inside the loop)
    {
        const float* src = Qp + sr * HD + sc;
        float4 v0 = *(const float4*)(src);
        float4 v1 = *(const float4*)(src + 4);
        float4 v2 = *(const float4*)(src + 8);
        float4 v3 = *(const float4*)(src + 12);
        *(float4*)&Qs[sr][sc]      = v0;
        *(float4*)&Qs[sr][sc + 4]  = v1;
        *(float4*)&Qs[sr][sc + 8]  = v2;
        *(float4*)&Qs[sr][sc + 12] = v3;
    }

    float  m_i[4], l_i[4];
    float4 o_i[4];
    #pragma unroll
    for (int i = 0; i < 4; i++) {
        m_i[i] = -INFINITY; l_i[i] = 0.f;
        o_i[i] = make_float4(0.f, 0.f, 0.f, 0.f);
    }

    for (int kt = 0; kt < 16; kt++) {
        // issue K and V tile loads up front; V latency hides under QK^T+softmax
        const float* ksrc = Kp + (size_t)(kt * 64 + sr) * HD + sc;
        const float* vsrc = Vp + (size_t)(kt * 64 + sr) * HD + sc;
        float4 k0 = *(const float4*)(ksrc);
        float4 k1 = *(const float4*)(ksrc + 4);
        float4 k2 = *(const float4*)(ksrc + 8);
        float4 k3 = *(const float4*)(ksrc + 12);
        float4 v0 = *(const float4*)(vsrc);
        float4 v1 = *(const float4*)(vsrc + 4);
        float4 v2 = *(const float4*)(vsrc + 8);
        float4 v3 = *(const float4*)(vsrc + 12);

        __syncthreads();   // previous PV reads of KVs done (and Q staging, kt=0)
        *(float4*)&KVs[sr][sc]      = k0;
        *(float4*)&KVs[sr][sc + 4]  = k1;
        *(float4*)&KVs[sr][sc + 8]  = k2;
        *(float4*)&KVs[sr][sc + 12] = k3;
        __syncthreads();

        // S = Q_tile @ K_tile^T  (scores; Q pre-scaled)
        // thread: q-rows ty+16i (i=0..3), k-cols tx+16cc (cc=0..3)
        float s[4][4];
        #pragma unroll
        for (int i = 0; i < 4; i++)
            #pragma unroll
            for (int cc = 0; cc < 4; cc++) s[i][cc] = 0.f;

        #pragma unroll
        for (int d0 = 0; d0 < HD; d0 += 4) {
            float4 kf[4];
            #pragma unroll
            for (int cc = 0; cc < 4; cc++)
                kf[cc] = *(const float4*)&KVs[tx + 16 * cc][d0];
            #pragma unroll
            for (int i = 0; i < 4; i++) {
                float4 qf = *(const float4*)&Qs[ty + 16 * i][d0];
                #pragma unroll
                for (int cc = 0; cc < 4; cc++)
                    s[i][cc] += qf.x * kf[cc].x + qf.y * kf[cc].y
                              + qf.z * kf[cc].z + qf.w * kf[cc].w;
            }
        }

        // online softmax update; row r's 64 scores live in the 16 lanes sharing ty
        #pragma unroll
        for (int i = 0; i < 4; i++) {
            float tmax = fmaxf(fmaxf(s[i][0], s[i][1]), fmaxf(s[i][2], s[i][3]));
            #pragma unroll
            for (int off = 8; off; off >>= 1)
                tmax = fmaxf(tmax, __shfl_xor(tmax, off, 64));
            float mnew = fmaxf(m_i[i], tmax);
            float corr = __expf(m_i[i] - mnew);   // exp(-inf)=0 on first tile
            float p0 = __expf(s[i][0] - mnew);
            float p1 = __expf(s[i][1] - mnew);
            float p2 = __expf(s[i][2] - mnew);
            float p3 = __expf(s[i][3] - mnew);
            float psum = p0 + p1 + p2 + p3;
            #pragma unroll
            for (int off = 8; off; off >>= 1)
                psum += __shfl_xor(psum, off, 64);
            l_i[i] = l_i[i] * corr + psum;
            m_i[i] = mnew;
            o_i[i].x *= corr; o_i[i].y *= corr; o_i[i].z *= corr; o_i[i].w *= corr;
            Ps[ty + 16 * i][tx]      = p0;
            Ps[ty + 16 * i][tx + 16] = p1;
            Ps[ty + 16 * i][tx + 32] = p2;
            Ps[ty + 16 * i][tx + 48] = p3;
        }

        __syncthreads();   // all K reads done + Ps visible
        *(float4*)&KVs[sr][sc]      = v0;
        *(float4*)&KVs[sr][sc + 4]  = v1;
        *(float4*)&KVs[sr][sc + 8]  = v2;
        *(float4*)&KVs[sr][sc + 12] = v3;
        __syncthreads();

        // O += P @ V_tile; thread: rows ty+16i, d-cols tx*4..tx*4+3
        #pragma unroll
        for (int c0 = 0; c0 < 64; c0 += 4) {
            float4 vv[4];
            #pragma unroll
            for (int u = 0; u < 4; u++)
                vv[u] = *(const float4*)&KVs[c0 + u][tx * 4];
            #pragma unroll
            for (int i = 0; i < 4; i++) {
                float4 p4 = *(const float4*)&Ps[ty + 16 * i][c0];
                fma4(o_i[i], p4.x, vv[0]);
                fma4(o_i[i], p4.y, vv[1]);
                fma4(o_i[i], p4.z, vv[2]);
                fma4(o_i[i], p4.w, vv[3]);
            }
        }
    }

    // normalize and write attn output in [b, n, h*64+d] layout
    #pragma unroll
    for (int i = 0; i < 4; i++) {
        float inv = 1.0f / l_i[i];
        int n = qt * 64 + ty + 16 * i;
        float4 v = o_i[i];
        v.x *= inv; v.y *= inv; v.z *= inv; v.w *= inv;
        *(float4*)&O[(size_t)(b * 1024 + n) * 1024 + h * 64 + tx * 4] = v;
    }
}

extern "C" void kernel_launch(void* const* d_in, const int* in_sizes, int n_in,
                              void* d_out, int out_size, void* d_ws, size_t ws_size,
                              hipStream_t stream)
{
    const float* x    = (const float*)d_in[0];   // [8,1024,1024]
    const float* Wqkv = (const float*)d_in[1];   // [1024,3072]
    const float* Wout = (const float*)d_in[2];   // [1024,1024]
    float* out = (float*)d_out;                  // [8,1024,1024]
    float* ws  = (float*)d_ws;

    const size_t SZ = 8ull * 1024 * 1024;        // 8.4M floats per tensor
    float* Qb = ws;                              // [b,h,n,d], pre-scaled by 1/8
    float* Kb = ws + SZ;                         // [b,h,n,d]
    float* Vb = ws + 2 * SZ;                     // [b,h,n,d]
    float* AO = ws + 3 * SZ;                     // [8192,1024] attn output

    // qkv projection with head-layout scatter epilogue
    gemm_tile<1><<<dim3(3072 / 128, 8192 / 128), 256, 0, stream>>>(
        x, Wqkv, Qb, Kb, Vb, 8192, 1024, 3072);

    // flash attention: 16 q-tiles x 16 heads x 8 batches = 2048 blocks
    attn_kernel<<<dim3(16, NH, 8), 256, 0, stream>>>(Qb, Kb, Vb, AO);

    // output projection
    gemm_tile<0><<<dim3(1024 / 128, 8192 / 128), 256, 0, stream>>>(
        AO, Wout, out, nullptr, nullptr, 8192, 1024, 1024);
}

// Round 2
// 444.811 us; speedup vs baseline: 2.9245x; 2.9245x over previous
//
#include <hip/hip_runtime.h>
#include <math.h>

#define NH 16
#define HD 64

typedef unsigned short u16;
typedef unsigned int   u32;
using bf16x8 = __attribute__((ext_vector_type(8))) short;
using f32x4  = __attribute__((ext_vector_type(4))) float;
using u16x8  = __attribute__((ext_vector_type(8))) unsigned short;
using u16x4  = __attribute__((ext_vector_type(4))) unsigned short;

__device__ __forceinline__ u16 f2bf(float x) {
    u32 u = __float_as_uint(x);
    u32 r = (u + 0x7FFFu + ((u >> 16) & 1u)) >> 16;
    return (u16)r;
}
__device__ __forceinline__ float bf2f(u16 h) { return __uint_as_float(((u32)h) << 16); }

#define GLDS16(src, dst) __builtin_amdgcn_global_load_lds( \
    (const __attribute__((address_space(1))) void*)(src),  \
    (__attribute__((address_space(3))) void*)(dst), 16, 0, 0)

// ---------------------------------------------------------------------------
// x [8192][1024] f32 -> xt [8192][3072] bf16 blocks [hi | lo | hi]
__global__ __launch_bounds__(256) void convert_x(const float* __restrict__ x,
                                                 u16* __restrict__ xt) {
    int t = blockIdx.x * 256 + threadIdx.x;   // 1M threads, 8 elems each
    int m = t >> 7;
    int k = (t & 127) * 8;
    const float4* src = (const float4*)(x + (size_t)m * 1024 + k);
    float4 v0 = src[0], v1 = src[1];
    float vs[8] = {v0.x, v0.y, v0.z, v0.w, v1.x, v1.y, v1.z, v1.w};
    u16x8 hv, lv;
    #pragma unroll
    for (int j = 0; j < 8; j++) {
        u16 hi = f2bf(vs[j]);
        hv[j] = hi;
        lv[j] = f2bf(vs[j] - bf2f(hi));
    }
    u16* base = xt + (size_t)m * 3072 + k;
    *(u16x8*)(base)        = hv;
    *(u16x8*)(base + 1024) = lv;
    *(u16x8*)(base + 2048) = hv;
}

// ---------------------------------------------------------------------------
// W [K][N] f32 -> Wt [N][3K] bf16 blocks [hi | hi | lo]  (transposed)
__global__ __launch_bounds__(256) void conv_w(const float* __restrict__ W,
                                              u16* __restrict__ Wt, int K, int N) {
    __shared__ float Ts[32][33];
    int k0 = blockIdx.y * 32, n0 = blockIdx.x * 32;
    int t = threadIdx.x;
    int r = t >> 3, c4 = (t & 7) * 4;
    float4 v = *(const float4*)(W + (size_t)(k0 + r) * N + n0 + c4);
    Ts[r][c4] = v.x; Ts[r][c4 + 1] = v.y; Ts[r][c4 + 2] = v.z; Ts[r][c4 + 3] = v.w;
    __syncthreads();
    int nl = t >> 3, kl = (t & 7) * 4;
    u16x4 hv, lv;
    #pragma unroll
    for (int j = 0; j < 4; j++) {
        float f = Ts[kl + j][nl];
        u16 hi = f2bf(f);
        hv[j] = hi;
        lv[j] = f2bf(f - bf2f(hi));
    }
    u16* base = Wt + (size_t)(n0 + nl) * (3 * K) + k0 + kl;
    *(u16x4*)(base)         = hv;
    *(u16x4*)(base + K)     = hv;
    *(u16x4*)(base + 2 * K) = lv;
}

// ---------------------------------------------------------------------------
// V [head][1024 key][64 d] bf16 -> Vt [head][64 d][1024 key]
__global__ __launch_bounds__(256) void transpose_v(const u16* __restrict__ V,
                                                   u16* __restrict__ Vt) {
    __shared__ u16 T[64][72];
    int head = blockIdx.y, kt = blockIdx.x;
    const u16* src = V + ((size_t)head * 1024 + kt * 64) * 64;
    int t = threadIdx.x;
    int r = t >> 2, c = (t & 3) * 16;
    *(u16x8*)&T[r][c]     = *(const u16x8*)(src + r * 64 + c);
    *(u16x8*)&T[r][c + 8] = *(const u16x8*)(src + r * 64 + c + 8);
    __syncthreads();
    int d = t >> 2, kc = (t & 3) * 16;
    u16x8 o0, o1;
    #pragma unroll
    for (int j = 0; j < 8; j++) { o0[j] = T[kc + j][d]; o1[j] = T[kc + 8 + j][d]; }
    u16* dst = Vt + ((size_t)head * 64 + d) * 1024 + kt * 64 + kc;
    *(u16x8*)(dst)     = o0;
    *(u16x8*)(dst + 8) = o1;
}

// ---------------------------------------------------------------------------
// bf16 GEMM: A [M][Kp] row-major, Bt [N][Kp] row-major (= B^T). 128x128 tile,
// BK=64, 4 waves, 64x64 per wave (4x4 16x16x32 fragments).
// MODE 0: C f32 [M][N].  MODE 1: qkv scatter into head layouts.
template<int MODE>
__global__ __launch_bounds__(256, 2)
void gemm_bf16(const u16* __restrict__ A, const u16* __restrict__ Bt,
               float* __restrict__ C,
               u16* __restrict__ Qh, u16* __restrict__ Kh, u16* __restrict__ Vh,
               int M, int Kp, int N) {
    __shared__ u16 As[128 * 64];
    __shared__ u16 Bs[128 * 64];
    const char* AsC = (const char*)As;
    const char* BsC = (const char*)Bs;

    const int t = threadIdx.x;
    const int lane = t & 63, w = t >> 6;
    const int m0 = blockIdx.y * 128, n0 = blockIdx.x * 128;
    const int l15 = lane & 15;
    const int g16 = (lane >> 4) << 4;
    const int swz = (l15 & 7) << 4;

    // staging: 4 gload_lds per wave per matrix; linear LDS, pre-swizzled source
    const char* srcA[4];
    const char* srcB[4];
    char* dstA[4];
    char* dstB[4];
    #pragma unroll
    for (int i = 0; i < 4; i++) {
        int s = (w * 4 + i) * 64 + lane;
        int row  = (s * 16) >> 7;       // 128B per LDS row (64 bf16)
        int colb = (s * 16) & 127;
        int scol = colb ^ ((row & 7) << 4);
        srcA[i] = (const char*)A  + ((size_t)(m0 + row) * Kp) * 2 + scol;
        srcB[i] = (const char*)Bt + ((size_t)(n0 + row) * Kp) * 2 + scol;
        dstA[i] = (char*)As + (w * 4 + i) * 1024;
        dstB[i] = (char*)Bs + (w * 4 + i) * 1024;
    }

    const int wm = (w >> 1) * 64, wn = (w & 1) * 64;
    int rA[4], rB[4];
    #pragma unroll
    for (int i = 0; i < 4; i++) {
        rA[i] = (wm + i * 16 + l15) * 128;
        rB[i] = (wn + i * 16 + l15) * 128;
    }

    f32x4 acc[4][4];
    #pragma unroll
    for (int i = 0; i < 4; i++)
        #pragma unroll
        for (int j = 0; j < 4; j++)
            acc[i][j] = f32x4{0.f, 0.f, 0.f, 0.f};

    for (int k0 = 0; k0 < Kp; k0 += 64) {
        __syncthreads();
        #pragma unroll
        for (int i = 0; i < 4; i++) {
            GLDS16(srcA[i], dstA[i]);
            GLDS16(srcB[i], dstB[i]);
            srcA[i] += 128;
            srcB[i] += 128;
        }
        __syncthreads();
        #pragma unroll
        for (int kb = 0; kb < 2; kb++) {
            const int csw = ((kb << 6) | g16) ^ swz;
            bf16x8 af[4], bfr[4];
            #pragma unroll
            for (int mi = 0; mi < 4; mi++) af[mi]  = *(const bf16x8*)(AsC + rA[mi] + csw);
            #pragma unroll
            for (int ni = 0; ni < 4; ni++) bfr[ni] = *(const bf16x8*)(BsC + rB[ni] + csw);
            #pragma unroll
            for (int mi = 0; mi < 4; mi++)
                #pragma unroll
                for (int ni = 0; ni < 4; ni++)
                    acc[mi][ni] = __builtin_amdgcn_mfma_f32_16x16x32_bf16(
                        af[mi], bfr[ni], acc[mi][ni], 0, 0, 0);
        }
    }

    if (MODE == 0) {
        #pragma unroll
        for (int mi = 0; mi < 4; mi++) {
            int rowb = m0 + wm + mi * 16 + (lane >> 4) * 4;
            #pragma unroll
            for (int ni = 0; ni < 4; ni++) {
                int col = n0 + wn + ni * 16 + l15;
                #pragma unroll
                for (int reg = 0; reg < 4; reg++)
                    C[(size_t)(rowb + reg) * N + col] = acc[mi][ni][reg];
            }
        }
    } else {
        #pragma unroll
        for (int ni = 0; ni < 4; ni++) {
            int col = n0 + wn + ni * 16 + l15;
            int sel = col >> 10, within = col & 1023;
            int h = within >> 6, d = within & 63;
            #pragma unroll
            for (int mi = 0; mi < 4; mi++) {
                int rowb = m0 + wm + mi * 16 + (lane >> 4) * 4;
                #pragma unroll
                for (int reg = 0; reg < 4; reg++) {
                    int row = rowb + reg;
                    int bb = row >> 10, n = row & 1023;
                    size_t hn = (size_t)(bb * NH + h) * 1024 + n;
                    float v = acc[mi][ni][reg];
                    if (sel == 0) {
                        v *= 0.125f;                       // 1/sqrt(64), exact
                        u16 hi = f2bf(v);
                        u16 lo = f2bf(v - bf2f(hi));
                        u16* p = Qh + hn * 192 + d;
                        p[0] = hi; p[64] = lo; p[128] = hi;
                    } else if (sel == 1) {
                        u16 hi = f2bf(v);
                        u16 lo = f2bf(v - bf2f(hi));
                        u16* p = Kh + hn * 192 + d;
                        p[0] = hi; p[64] = hi; p[128] = lo;
                    } else {
                        Vh[hn * 64 + d] = f2bf(v);
                    }
                }
            }
        }
    }
}

// ---------------------------------------------------------------------------
// Flash attention, MFMA. Block = 4 waves; wave w owns q rows [qt*64+w*16, +16).
// Qh/Kh: [head][1024][192] bf16 (split K'); Vt: [head][64][1024] bf16.
// AO out: [8192][3072] bf16 [hi | lo | hi].
__global__ __launch_bounds__(256, 2)
void attn_mfma(const u16* __restrict__ Qh, const u16* __restrict__ Kh,
               const u16* __restrict__ Vt, u16* __restrict__ AO) {
    __shared__ u16 Qs[64 * 192];
    __shared__ u16 Ks[64 * 192];
    __shared__ u16 Vs[64 * 64];
    __shared__ u16 Ps[4][16 * 64];

    const int t = threadIdx.x, lane = t & 63, w = t >> 6;
    const int qt = blockIdx.x, h = blockIdx.y, b = blockIdx.z;
    const size_t head = (size_t)(b * NH + h);

    const char* Qg = (const char*)(Qh + head * 1024 * 192) + qt * 64 * 384;
    const char* Kg = (const char*)(Kh + head * 1024 * 192);
    const char* Vg = (const char*)(Vt + head * 64 * 1024);
    char* QsC = (char*)Qs;
    char* KsC = (char*)Ks;
    char* VsC = (char*)Vs;
    char* PsC = (char*)(&Ps[w][0]);

    const int l15 = lane & 15;
    const int g16 = (lane >> 4) << 4;
    const int swz = (l15 & 7) << 4;

    // stage Q (once): 64 rows x 384B, 6 gload per wave; remember geometry for K
    int kbase[6];
    #pragma unroll
    for (int i = 0; i < 6; i++) {
        int byte = ((w * 6 + i) * 64 + lane) * 16;
        int row  = byte / 384;
        int colb = byte - row * 384;
        kbase[i] = row * 384 + (colb ^ ((row & 7) << 4));
        GLDS16(Qg + kbase[i], QsC + (w * 6 + i) * 1024);
    }
    int vbase[2];
    #pragma unroll
    for (int i = 0; i < 2; i++) {
        int byte = ((w * 2 + i) * 64 + lane) * 16;
        int row  = byte >> 7;
        int colb = byte & 127;
        vbase[i] = row * 2048 + (colb ^ ((row & 7) << 4));
    }

    float m_r[4] = {-INFINITY, -INFINITY, -INFINITY, -INFINITY};
    float l_r[4] = {0.f, 0.f, 0.f, 0.f};
    f32x4 acc_o[4];
    #pragma unroll
    for (int i = 0; i < 4; i++) acc_o[i] = f32x4{0.f, 0.f, 0.f, 0.f};

    const int qrow = w * 16 + l15;           // A-frag row (local q), swz = (l15&7)

    for (int kt = 0; kt < 16; kt++) {
        __syncthreads();
        #pragma unroll
        for (int i = 0; i < 6; i++)
            GLDS16(Kg + (size_t)kt * 24576 + kbase[i], KsC + (w * 6 + i) * 1024);
        #pragma unroll
        for (int i = 0; i < 2; i++)
            GLDS16(Vg + kt * 128 + vbase[i], VsC + (w * 2 + i) * 1024);
        __syncthreads();

        // S = Q K^T over K'=192 (3-term split)
        f32x4 sacc[4];
        #pragma unroll
        for (int c = 0; c < 4; c++) sacc[c] = f32x4{0.f, 0.f, 0.f, 0.f};
        #pragma unroll
        for (int ks = 0; ks < 6; ks++) {
            int qoff = qrow * 384 + (((ks * 64) | g16) ^ swz);
            bf16x8 aq = *(const bf16x8*)(QsC + qoff);
            #pragma unroll
            for (int c = 0; c < 4; c++) {
                int krow = c * 16 + l15;
                int koff = krow * 384 + (((ks * 64) | g16) ^ swz);
                bf16x8 bk = *(const bf16x8*)(KsC + koff);
                sacc[c] = __builtin_amdgcn_mfma_f32_16x16x32_bf16(aq, bk, sacc[c], 0, 0, 0);
            }
        }

        // online softmax per accumulator row; write P (bf16) to wave-private LDS
        #pragma unroll
        for (int reg = 0; reg < 4; reg++) {
            float s0 = sacc[0][reg], s1 = sacc[1][reg];
            float s2 = sacc[2][reg], s3 = sacc[3][reg];
            float tmax = fmaxf(fmaxf(s0, s1), fmaxf(s2, s3));
            #pragma unroll
            for (int off = 8; off; off >>= 1)
                tmax = fmaxf(tmax, __shfl_xor(tmax, off, 64));
            float mnew = fmaxf(m_r[reg], tmax);
            float corr = __expf(m_r[reg] - mnew);
            float p0 = __expf(s0 - mnew), p1 = __expf(s1 - mnew);
            float p2 = __expf(s2 - mnew), p3 = __expf(s3 - mnew);
            float ps = p0 + p1 + p2 + p3;
            #pragma unroll
            for (int off = 8; off; off >>= 1)
                ps += __shfl_xor(ps, off, 64);
            l_r[reg] = l_r[reg] * corr + ps;
            m_r[reg] = mnew;
            #pragma unroll
            for (int c2 = 0; c2 < 4; c2++) acc_o[c2][reg] *= corr;
            int prow = (lane >> 4) * 4 + reg;
            int swzp = (prow & 7) << 4;
            char* pb = PsC + prow * 128;
            *(u16*)(pb + ((2 * l15)        ^ swzp)) = f2bf(p0);
            *(u16*)(pb + ((2 * (l15 + 16)) ^ swzp)) = f2bf(p1);
            *(u16*)(pb + ((2 * (l15 + 32)) ^ swzp)) = f2bf(p2);
            *(u16*)(pb + ((2 * (l15 + 48)) ^ swzp)) = f2bf(p3);
        }

        // O += P @ V (Ps is wave-private: no barrier needed)
        #pragma unroll
        for (int kb = 0; kb < 2; kb++) {
            int pcol = ((kb << 6) | g16) ^ swz;
            bf16x8 ap = *(const bf16x8*)(PsC + l15 * 128 + pcol);
            #pragma unroll
            for (int c2 = 0; c2 < 4; c2++) {
                int vrow = c2 * 16 + l15;
                int voff = vrow * 128 + (((kb << 6) | g16) ^ ((vrow & 7) << 4));
                bf16x8 bv = *(const bf16x8*)(VsC + voff);
                acc_o[c2] = __builtin_amdgcn_mfma_f32_16x16x32_bf16(ap, bv, acc_o[c2], 0, 0, 0);
            }
        }
    }

    // epilogue: normalize, split hi/lo, write AO [hi | lo | hi]
    #pragma unroll
    for (int c2 = 0; c2 < 4; c2++) {
        int col = h * 64 + c2 * 16 + l15;
        #pragma unroll
        for (int reg = 0; reg < 4; reg++) {
            int row = b * 1024 + qt * 64 + w * 16 + (lane >> 4) * 4 + reg;
            float v = acc_o[c2][reg] / l_r[reg];
            u16 hi = f2bf(v);
            u16 lo = f2bf(v - bf2f(hi));
            u16* p = AO + (size_t)row * 3072 + col;
            p[0] = hi; p[1024] = lo; p[2048] = hi;
        }
    }
}

// ---------------------------------------------------------------------------
extern "C" void kernel_launch(void* const* d_in, const int* in_sizes, int n_in,
                              void* d_out, int out_size, void* d_ws, size_t ws_size,
                              hipStream_t stream) {
    const float* x    = (const float*)d_in[0];   // [8,1024,1024]
    const float* Wqkv = (const float*)d_in[1];   // [1024,3072]
    const float* Wout = (const float*)d_in[2];   // [1024,1024]
    float* out = (float*)d_out;                  // [8,1024,1024] f32

    u16* xt    = (u16*)d_ws;                     // [8192][3072]
    u16* wqkvt = xt + 8192ull * 3072;            // [3072][3072]
    u16* woutt = wqkvt + 3072ull * 3072;         // [1024][3072]
    u16* Qh    = woutt + 1024ull * 3072;         // [128][1024][192]
    u16* Kh    = Qh + 128ull * 1024 * 192;       // [128][1024][192]
    u16* Vh    = Kh + 128ull * 1024 * 192;       // [128][1024][64]
    u16* Vtr   = Vh + 128ull * 1024 * 64;        // [128][64][1024]
    u16* AO    = xt;                             // alias: xt dead after qkv GEMM

    convert_x<<<4096, 256, 0, stream>>>(x, xt);
    conv_w<<<dim3(96, 32), 256, 0, stream>>>(Wqkv, wqkvt, 1024, 3072);
    conv_w<<<dim3(32, 32), 256, 0, stream>>>(Wout, woutt, 1024, 1024);

    gemm_bf16<1><<<dim3(24, 64), 256, 0, stream>>>(
        xt, wqkvt, nullptr, Qh, Kh, Vh, 8192, 3072, 3072);

    transpose_v<<<dim3(16, 128), 256, 0, stream>>>(Vh, Vtr);

    attn_mfma<<<dim3(16, NH, 8), 256, 0, stream>>>(Qh, Kh, Vtr, AO);

    gemm_bf16<0><<<dim3(8, 64), 256, 0, stream>>>(
        AO, woutt, out, nullptr, nullptr, nullptr, 8192, 3072, 1024);
}